// Round 9
// baseline (461.956 us; speedup 1.0000x reference)
//
#include <hip/hip_runtime.h>
#include <hip/hip_bf16.h>

#define B_N 2048
#define D_N 4096
#define H_N 1024
#define L_N 64
#define NTILE 136  // 16*17/2 lower-triangle 128x128 tiles of the 2048x2048 d2 matrix
#define SPLK 4     // split-K for the two K=4096 GEMMs
#define NNK 16     // exact top-k neighbor list length for Boruvka fast path

typedef __attribute__((ext_vector_type(8))) short short8;
typedef __attribute__((ext_vector_type(4))) float float4_t;

#define ASG __attribute__((address_space(1)))
#define ASL __attribute__((address_space(3)))

__device__ inline float bf2f(unsigned short u) {
  union { unsigned u; float f; } v; v.u = ((unsigned)u) << 16; return v.f;
}
__device__ inline unsigned short f2bf(float f) {
  union { float f; unsigned u; } v; v.f = f;
  unsigned r = v.u + 0x7fffu + ((v.u >> 16) & 1u);
  return (unsigned short)(r >> 16);
}

__device__ inline float block_sum256(float v) {
  const int lane = threadIdx.x & 63, wave = threadIdx.x >> 6;
#pragma unroll
  for (int off = 32; off; off >>= 1) v += __shfl_xor(v, off);
  __shared__ float red_s[4];
  if (lane == 0) red_s[wave] = v;
  __syncthreads();
  return red_s[0] + red_s[1] + red_s[2] + red_s[3];
}

__device__ inline float block_max256(float v) {
  const int lane = threadIdx.x & 63, wave = threadIdx.x >> 6;
#pragma unroll
  for (int off = 32; off; off >>= 1) v = fmaxf(v, __shfl_xor(v, off));
  __shared__ float redm_s[4];
  if (lane == 0) redm_s[wave] = v;
  __syncthreads();
  return fmaxf(fmaxf(redm_s[0], redm_s[1]), fmaxf(redm_s[2], redm_s[3]));
}

// triangular tile index -> (tm, tn), tn <= tm
__device__ inline void tri_idx(int b, int& tm, int& tn) {
  int m = (int)((sqrtf(8.f * (float)b + 1.f) - 1.f) * 0.5f);
  while ((m + 1) * (m + 2) / 2 <= b) ++m;
  while (m * (m + 1) / 2 > b) --m;
  tm = m;
  tn = b - m * (m + 1) / 2;
}

// ---------------- prep kernels ----------------

// cast x row to bf16 K-panel layout + row sum of squares; block B_N = state init
__global__ __launch_bounds__(256) void prep_x(const float* __restrict__ x,
                                              unsigned short* __restrict__ xb,
                                              float* __restrict__ sqx,
                                              float* __restrict__ accum,
                                              int* __restrict__ comp,
                                              int* __restrict__ cnt,
                                              int* __restrict__ done) {
  const int row = blockIdx.x;
  const int t = threadIdx.x;
  if (row == B_N) {  // init block
    if (t < 2) { accum[t] = 0.f; cnt[t] = 0; done[t] = 0; }
    for (int v = t; v < 2 * B_N; v += 256) comp[v] = v & (B_N - 1);
    return;
  }
  const float4* xr = (const float4*)(x + (size_t)row * D_N);
  float s = 0.f;
  for (int i = t; i < D_N / 4; i += 256) {
    float4 v = xr[i];
    s += v.x * v.x + v.y * v.y + v.z * v.z + v.w * v.w;
    ushort4 o;
    o.x = f2bf(v.x); o.y = f2bf(v.y); o.z = f2bf(v.z); o.w = f2bf(v.w);
    const int p = i >> 3;
    const int k31 = (4 * i) & 31;
    *(ushort4*)(xb + ((size_t)p * B_N + row) * 32 + k31) = o;
  }
  float tot = block_sum256(s);
  if (t == 0) sqx[row] = tot;
}

// both weight transposes (K-panel layout) in one dispatch; 1D grid 8192, block (32,8)
__global__ __launch_bounds__(256) void transpose2(const float* __restrict__ W1,
                                                  const float* __restrict__ W4,
                                                  unsigned short* __restrict__ w1bt,
                                                  unsigned short* __restrict__ w4bt) {
  __shared__ float tile[32][33];
  int b = blockIdx.x;
  const float* in;
  unsigned short* out;
  int C, bx, by;
  if (b < 4096) { in = W1; out = w1bt; C = H_N; bx = b & 31;  by = b >> 5; }
  else { b -= 4096; in = W4; out = w4bt; C = D_N; bx = b & 127; by = b >> 7; }
  const int c0 = bx * 32, r0 = by * 32;
  const int tx = threadIdx.x, ty = threadIdx.y;
#pragma unroll
  for (int i = 0; i < 32; i += 8)
    tile[ty + i][tx] = in[(size_t)(r0 + ty + i) * C + c0 + tx];
  __syncthreads();
#pragma unroll
  for (int i = 0; i < 32; i += 8)
    out[((size_t)(r0 >> 5) * C + c0 + ty + i) * 32 + tx] = f2bf(tile[tx][ty + i]);
}

// ---------------- MFMA GEMM mainloop (128x128 tile, BK=32, 256 threads) ----------------

__device__ inline void gemm_mainloop(const unsigned short* __restrict__ A,
                                     const unsigned short* __restrict__ Bt,
                                     int nrA, int nrB, int Klen, int m_base, int n_base,
                                     float4_t acc[4][4]) {
  __shared__ unsigned short lA[128 * 32];
  __shared__ unsigned short lB[128 * 32];
  const int t = threadIdx.x;
  const int wave = t >> 6;
  const int lane = t & 63;
  const int lrow = lane & 15;
  const int quad = lane >> 4;
  const int wm = (wave & 1) * 64;
  const int wn = (wave >> 1) * 64;

  const int srow = lane >> 2;
  const int scol = (lane & 3) * 8;

  for (int k0 = 0; k0 < Klen; k0 += 32) {
    const size_t pA = (size_t)(k0 >> 5) * nrA;
    const size_t pB = (size_t)(k0 >> 5) * nrB;
    __syncthreads();
#pragma unroll
    for (int q = 0; q < 2; ++q) {
      const int rbase = wave * 32 + q * 16;
      const int row = rbase + srow;
      __builtin_amdgcn_global_load_lds(
          (ASG void*)(A + (pA + m_base + row) * 32 + scol),
          (ASL void*)(lA + rbase * 32), 16, 0, 0);
      __builtin_amdgcn_global_load_lds(
          (ASG void*)(Bt + (pB + n_base + row) * 32 + scol),
          (ASL void*)(lB + rbase * 32), 16, 0, 0);
    }
    __syncthreads();
    short8 af[4], bfr[4];
#pragma unroll
    for (int f = 0; f < 4; ++f) {
      af[f]  = *(const short8*)(lA + (wm + f * 16 + lrow) * 32 + quad * 8);
      bfr[f] = *(const short8*)(lB + (wn + f * 16 + lrow) * 32 + quad * 8);
    }
#pragma unroll
    for (int fm = 0; fm < 4; ++fm)
#pragma unroll
      for (int fn = 0; fn < 4; ++fn)
        acc[fm][fn] = __builtin_amdgcn_mfma_f32_16x16x32_bf16(af[fm], bfr[fn],
                                                              acc[fm][fn], 0, 0, 0);
  }
}

// split-K partial GEMM (rectangular): blockIdx.z = split s. N = output cols.
__global__ __launch_bounds__(256) void gemm_splitk(const unsigned short* __restrict__ A,
                                                   const unsigned short* __restrict__ Bt,
                                                   int nrA, int nrB, int Kchunk, int N,
                                                   float* __restrict__ partial) {
  float4_t acc[4][4];
  float4_t z4 = {0.f, 0.f, 0.f, 0.f};
#pragma unroll
  for (int a = 0; a < 4; ++a)
#pragma unroll
    for (int b = 0; b < 4; ++b) acc[a][b] = z4;
  const int s = blockIdx.z;
  const int m_base = blockIdx.y * 128, n_base = blockIdx.x * 128;
  const size_t po = (size_t)(s * (Kchunk >> 5));
  gemm_mainloop(A + po * nrA * 32, Bt + po * nrB * 32, nrA, nrB, Kchunk,
                m_base, n_base, acc);
  const size_t MN = (size_t)gridDim.y * 128 * N;
  float* __restrict__ P = partial + (size_t)s * MN;
  const int t = threadIdx.x, wave = t >> 6, lane = t & 63;
  const int lrow = lane & 15, quad = lane >> 4;
  const int wm = (wave & 1) * 64, wn = (wave >> 1) * 64;
#pragma unroll
  for (int fm = 0; fm < 4; ++fm)
#pragma unroll
    for (int fn = 0; fn < 4; ++fn) {
      const int r0 = m_base + wm + fm * 16 + quad * 4;
      const int c = n_base + wn + fn * 16 + lrow;
#pragma unroll
      for (int r = 0; r < 4; ++r)
        P[(size_t)(r0 + r) * N + c] = acc[fm][fn][r];
    }
}

// d2 split-K over lower-triangle tiles. Partial: tile-local row-major.
__global__ __launch_bounds__(256) void gemm_d2_tri(const unsigned short* __restrict__ xb,
                                                   float* __restrict__ partial) {
  float4_t acc[4][4];
  float4_t z4 = {0.f, 0.f, 0.f, 0.f};
#pragma unroll
  for (int a = 0; a < 4; ++a)
#pragma unroll
    for (int b = 0; b < 4; ++b) acc[a][b] = z4;
  const int s = blockIdx.z;
  int tm, tn;
  tri_idx(blockIdx.x, tm, tn);
  const size_t po = (size_t)(s * ((D_N / SPLK) >> 5)) * B_N * 32;
  gemm_mainloop(xb + po, xb + po, B_N, B_N, D_N / SPLK, tm * 128, tn * 128, acc);
  float* __restrict__ P = partial + ((size_t)s * NTILE + blockIdx.x) * 16384;
  const int t = threadIdx.x, wave = t >> 6, lane = t & 63;
  const int lrow = lane & 15, quad = lane >> 4;
  const int wm = (wave & 1) * 64, wn = (wave >> 1) * 64;
#pragma unroll
  for (int fm = 0; fm < 4; ++fm)
#pragma unroll
    for (int fn = 0; fn < 4; ++fn) {
      const int lr0 = wm + fm * 16 + quad * 4;
      const int lc = wn + fn * 16 + lrow;
#pragma unroll
      for (int r = 0; r < 4; ++r)
        P[(lr0 + r) * 128 + lc] = acc[fm][fn][r];
    }
}

// finalize G1: h1 = bf16(relu(sum_s partial + b1)), written K-panel packed (k over H)
__global__ __launch_bounds__(256) void fin_bias_relu(const float* __restrict__ partial,
                                                     const float* __restrict__ bias,
                                                     unsigned short* __restrict__ out) {
  const size_t MN = (size_t)B_N * H_N;
  const size_t i4 = ((size_t)blockIdx.x * 256 + threadIdx.x) * 4;
  float4 a = *(const float4*)(partial + i4);
#pragma unroll
  for (int s = 1; s < SPLK; ++s) {
    float4 p = *(const float4*)(partial + s * MN + i4);
    a.x += p.x; a.y += p.y; a.z += p.z; a.w += p.w;
  }
  const int row = (int)(i4 >> 10);
  const int k = (int)(i4 & (H_N - 1));
  float4 b = *(const float4*)(bias + k);
  ushort4 o;
  o.x = f2bf(fmaxf(a.x + b.x, 0.f));
  o.y = f2bf(fmaxf(a.y + b.y, 0.f));
  o.z = f2bf(fmaxf(a.z + b.z, 0.f));
  o.w = f2bf(fmaxf(a.w + b.w, 0.f));
  *(ushort4*)(out + ((size_t)(k >> 5) * B_N + row) * 32 + (k & 31)) = o;
}

// finalize d2 (triangular): sum SPLK splits, v = max(sq_i+sq_j-2*dot, 0), write (i,j)
// coalesced, mirror (j,i) via LDS chunk transpose, track global max. grid (4, NTILE)
__global__ __launch_bounds__(256) void fin_d2_tri(const float* __restrict__ partial,
                                                  const float* __restrict__ sq,
                                                  float* __restrict__ Out,
                                                  unsigned* __restrict__ max_slot) {
  const int tile = blockIdx.y;
  const int c0 = blockIdx.x * 32;
  int tm, tn;
  tri_idx(tile, tm, tn);
  __shared__ float lds[32][132];
  const int t = threadIdx.x;
  const int cc = (t & 7) * 4;
  float lmax = 0.f;
#pragma unroll
  for (int q = 0; q < 4; ++q) {
    const int r = (t >> 3) + 32 * q;
    const float* base = partial + (size_t)tile * 16384 + r * 128 + c0 + cc;
    float4 a = *(const float4*)base;
#pragma unroll
    for (int s = 1; s < SPLK; ++s) {
      float4 p = *(const float4*)(base + (size_t)s * NTILE * 16384);
      a.x += p.x; a.y += p.y; a.z += p.z; a.w += p.w;
    }
    const int i = tm * 128 + r;
    const float si = sq[i];
    float4 sj = *(const float4*)(sq + tn * 128 + c0 + cc);
    float4 v;
    v.x = fmaxf(si + sj.x - 2.f * a.x, 0.f);
    v.y = fmaxf(si + sj.y - 2.f * a.y, 0.f);
    v.z = fmaxf(si + sj.z - 2.f * a.z, 0.f);
    v.w = fmaxf(si + sj.w - 2.f * a.w, 0.f);
    *(float4*)(Out + (size_t)i * B_N + tn * 128 + c0 + cc) = v;
    lds[cc + 0][r] = v.x;
    lds[cc + 1][r] = v.y;
    lds[cc + 2][r] = v.z;
    lds[cc + 3][r] = v.w;
    lmax = fmaxf(lmax, fmaxf(fmaxf(v.x, v.y), fmaxf(v.z, v.w)));
  }
  __syncthreads();
#pragma unroll
  for (int m = 0; m < 4; ++m) {
    const int lin = t + 256 * m;
    const int cc2 = lin >> 5;
    const int r4 = (lin & 31) * 4;
    float4 w = *(const float4*)(&lds[cc2][r4]);
    *(float4*)(Out + (size_t)(tn * 128 + c0 + cc2) * B_N + tm * 128 + r4) = w;
  }
  float tot = block_max256(lmax);
  if (t == 0) atomicMax(max_slot, __float_as_uint(tot));
}

// recloss GEMM (K=1024, 512 blocks): sum((C + bias - Xref)^2) -> atomicAdd
__global__ __launch_bounds__(256) void gemm_recloss(const unsigned short* __restrict__ A,
                                                    const unsigned short* __restrict__ Bt,
                                                    const float* __restrict__ bias,
                                                    const float* __restrict__ Xref,
                                                    float* __restrict__ acc_slot) {
  float4_t acc[4][4];
  float4_t z4 = {0.f, 0.f, 0.f, 0.f};
#pragma unroll
  for (int a = 0; a < 4; ++a)
#pragma unroll
    for (int b = 0; b < 4; ++b) acc[a][b] = z4;
  const int m_base = blockIdx.y * 128, n_base = blockIdx.x * 128;
  gemm_mainloop(A, Bt, B_N, D_N, H_N, m_base, n_base, acc);
  const int t = threadIdx.x, wave = t >> 6, lane = t & 63;
  const int lrow = lane & 15, quad = lane >> 4;
  const int wm = (wave & 1) * 64, wn = (wave >> 1) * 64;
  float local = 0.f;
#pragma unroll
  for (int fm = 0; fm < 4; ++fm)
#pragma unroll
    for (int fn = 0; fn < 4; ++fn) {
      const int r0 = m_base + wm + fm * 16 + quad * 4;
      const int c = n_base + wn + fn * 16 + lrow;
      const float bc = bias[c];
#pragma unroll
      for (int r = 0; r < 4; ++r) {
        float v = acc[fm][fn][r] + bc - Xref[(size_t)(r0 + r) * D_N + c];
        local += v * v;
      }
    }
  float tot = block_sum256(local);
  if (t == 0) atomicAdd(acc_slot, tot);
}

// ---------------- small vector kernels ----------------

// z = h1(bf16, panel-packed) @ W2 + b2, fused sqz (one wave per row)
__global__ __launch_bounds__(256) void g2_k(const unsigned short* __restrict__ h1b,
                                            const float* __restrict__ W2,
                                            const float* __restrict__ b2,
                                            float* __restrict__ z,
                                            float* __restrict__ sqz) {
  const int col = threadIdx.x & 63;
  const int row = blockIdx.x * 4 + (threadIdx.x >> 6);
  float a0 = 0.f, a1 = 0.f, a2 = 0.f, a3 = 0.f;
  for (int p = 0; p < H_N / 32; ++p) {
    const unsigned short* hb = h1b + ((size_t)p * B_N + row) * 32;
    const float* wb = W2 + (p * 32) * L_N + col;
#pragma unroll
    for (int k2 = 0; k2 < 32; k2 += 4) {
      a0 += bf2f(hb[k2 + 0]) * wb[(k2 + 0) * L_N];
      a1 += bf2f(hb[k2 + 1]) * wb[(k2 + 1) * L_N];
      a2 += bf2f(hb[k2 + 2]) * wb[(k2 + 2) * L_N];
      a3 += bf2f(hb[k2 + 3]) * wb[(k2 + 3) * L_N];
    }
  }
  const float zv = (a0 + a1) + (a2 + a3) + b2[col];
  z[(size_t)row * L_N + col] = zv;
  float s = zv * zv;
#pragma unroll
  for (int off = 32; off; off >>= 1) s += __shfl_xor(s, off);
  if (col == 0) sqz[row] = s;
}

// h2 = bf16(relu(z @ W3 + b3)), written K-panel packed (k over H)
__global__ __launch_bounds__(256) void g3_k(const float* __restrict__ z,
                                            const float* __restrict__ W3,
                                            const float* __restrict__ b3,
                                            unsigned short* __restrict__ h2b) {
  const int t = threadIdx.x;
  const int col = blockIdx.y * 256 + t;
  const int r0 = blockIdx.x * 4;
  __shared__ float zr[4][64];
  zr[t >> 6][t & 63] = z[(size_t)(r0 + (t >> 6)) * L_N + (t & 63)];
  __syncthreads();
  const float bc = b3[col];
  float a0 = bc, a1 = bc, a2 = bc, a3 = bc;
#pragma unroll 8
  for (int k = 0; k < 64; ++k) {
    float w = W3[k * H_N + col];
    a0 += zr[0][k] * w;
    a1 += zr[1][k] * w;
    a2 += zr[2][k] * w;
    a3 += zr[3][k] * w;
  }
  const size_t base = ((size_t)(col >> 5) * B_N) * 32 + (col & 31);
  h2b[base + (size_t)(r0 + 0) * 32] = f2bf(fmaxf(a0, 0.f));
  h2b[base + (size_t)(r0 + 1) * 32] = f2bf(fmaxf(a1, 0.f));
  h2b[base + (size_t)(r0 + 2) * 32] = f2bf(fmaxf(a2, 0.f));
  h2b[base + (size_t)(r0 + 3) * 32] = f2bf(fmaxf(a3, 0.f));
}

__global__ __launch_bounds__(256) void d2z_k(const float* __restrict__ z,
                                             const float* __restrict__ sqz,
                                             float* __restrict__ d2z) {
  const int bi = blockIdx.y * 16, bj = blockIdx.x * 16;
  __shared__ float zi[16][65], zj[16][65];
  const int t = threadIdx.x;
  for (int idx = t; idx < 16 * 64; idx += 256) {
    const int r = idx >> 6, c = idx & 63;
    zi[r][c] = z[(size_t)(bi + r) * L_N + c];
    zj[r][c] = z[(size_t)(bj + r) * L_N + c];
  }
  __syncthreads();
  const int ti = t >> 4, tj = t & 15;
  float dot = 0.f;
#pragma unroll 8
  for (int k = 0; k < 64; ++k) dot += zi[ti][k] * zj[tj][k];
  float v = fmaxf(sqz[bi + ti] + sqz[bj + tj] - 2.f * dot, 0.f);
  d2z[(size_t)(bi + ti) * B_N + bj + tj] = v;
}

// ---------------- exact top-NNK neighbor lists (for Boruvka fast path) ----------------
// key = (d2_bits<<32)|(i<<11)|j, globally distinct. Per (row, tree): NNK smallest keys
// ascending, self excluded. Register-resident selection, 16 block-reduce passes.
__global__ __launch_bounds__(256) void topk_k(const float* __restrict__ d2x,
                                              const float* __restrict__ d2z,
                                              unsigned long long* __restrict__ nn) {
  const int tree = blockIdx.y;
  const float* __restrict__ d2 = tree ? d2z : d2x;
  const int i = blockIdx.x;
  const int t = threadIdx.x;
  const float* __restrict__ row = d2 + (size_t)i * B_N;
  const unsigned ibase = (unsigned)(i << 11);
  float4 v0 = *(const float4*)(row + t * 8);
  float4 v1 = *(const float4*)(row + t * 8 + 4);
  unsigned long long key[8];
  const float vv[8] = {v0.x, v0.y, v0.z, v0.w, v1.x, v1.y, v1.z, v1.w};
#pragma unroll
  for (int q = 0; q < 8; ++q) {
    const int j = t * 8 + q;
    key[q] = (j == i) ? ~0ull
                      : ((((unsigned long long)__float_as_uint(vv[q])) << 32) |
                         (ibase | (unsigned)j));
  }
  unsigned long long* __restrict__ out = nn + ((size_t)tree * B_N + i) * NNK;
  __shared__ unsigned long long wmin_s[4];
  const int lane = t & 63, wave = t >> 6;
  for (int p = 0; p < NNK; ++p) {
    unsigned long long k = key[0];
#pragma unroll
    for (int q = 1; q < 8; ++q) k = key[q] < k ? key[q] : k;
#pragma unroll
    for (int off = 32; off; off >>= 1) {
      unsigned long long o = __shfl_xor(k, off);
      k = o < k ? o : k;
    }
    if (lane == 0) wmin_s[wave] = k;
    __syncthreads();
    unsigned long long a = wmin_s[0] < wmin_s[1] ? wmin_s[0] : wmin_s[1];
    unsigned long long b = wmin_s[2] < wmin_s[3] ? wmin_s[2] : wmin_s[3];
    const unsigned long long w = a < b ? a : b;
    if (t == 0) out[p] = w;
#pragma unroll
    for (int q = 0; q < 8; ++q)
      if (key[q] == w) key[q] = ~0ull;  // claim (keys distinct)
    __syncthreads();
  }
}

// ---------------- Boruvka MST: NN fast-path scan + LDS-atomic merge ----------------
// Fast path: first NN entry (ascending) with comp != comp(i) is provably row i's
// exact min cross-key. If all NNK are internal -> full row scan (exact fallback).
__global__ __launch_bounds__(256) void bor_scan(const float* __restrict__ d2x,
                                                const float* __restrict__ d2z,
                                                const int* __restrict__ comp,
                                                const unsigned long long* __restrict__ nn,
                                                unsigned long long* __restrict__ rowbest,
                                                const int* __restrict__ done) {
  const int tree = blockIdx.y;
  if (done[tree]) return;
  const float* __restrict__ d2 = tree ? d2z : d2x;
  const int* __restrict__ cp = comp + tree * B_N;
  const int i = blockIdx.x;
  const int t = threadIdx.x;
  const int ci = cp[i];
  __shared__ unsigned long long fastkey;
  __shared__ int needfull;
  if (t < 64) {
    unsigned long long k = ~0ull;
    bool cross = false;
    if (t < NNK) {
      k = nn[((size_t)tree * B_N + i) * NNK + t];
      cross = cp[(unsigned)k & (unsigned)(B_N - 1)] != ci;
    }
    const unsigned long long m = __ballot(cross);
    if (t == 0) needfull = (m == 0ull);
    if (m) {
      const int wl = __builtin_ctzll(m);
      if (t == wl) fastkey = k;
    }
  }
  __syncthreads();
  if (!needfull) {
    if (t == 0) rowbest[tree * B_N + i] = fastkey;
    return;
  }
  // full scan fallback
  const float* __restrict__ row = d2 + (size_t)i * B_N;
  const unsigned ibase = (unsigned)(i << 11);
  unsigned long long k = ~0ull;
#pragma unroll
  for (int m = 0; m < 2; ++m) {
    const int j4 = (t + m * 256) * 4;
    float4 dv = *(const float4*)(row + j4);
    int4 cj = *(const int4*)(cp + j4);
    if (cj.x != ci) {
      unsigned long long key = (((unsigned long long)__float_as_uint(dv.x)) << 32) | (ibase | (unsigned)(j4 + 0));
      k = key < k ? key : k;
    }
    if (cj.y != ci) {
      unsigned long long key = (((unsigned long long)__float_as_uint(dv.y)) << 32) | (ibase | (unsigned)(j4 + 1));
      k = key < k ? key : k;
    }
    if (cj.z != ci) {
      unsigned long long key = (((unsigned long long)__float_as_uint(dv.z)) << 32) | (ibase | (unsigned)(j4 + 2));
      k = key < k ? key : k;
    }
    if (cj.w != ci) {
      unsigned long long key = (((unsigned long long)__float_as_uint(dv.w)) << 32) | (ibase | (unsigned)(j4 + 3));
      k = key < k ? key : k;
    }
  }
  const int lane = t & 63, wave = t >> 6;
#pragma unroll
  for (int off = 32; off; off >>= 1) {
    unsigned long long o = __shfl_xor(k, off);
    k = o < k ? o : k;
  }
  __shared__ unsigned long long wmin[4];
  if (lane == 0) wmin[wave] = k;
  __syncthreads();
  if (t == 0) {
    unsigned long long a = wmin[0] < wmin[1] ? wmin[0] : wmin[1];
    unsigned long long b = wmin[2] < wmin[3] ? wmin[2] : wmin[3];
    rowbest[tree * B_N + i] = (a < b) ? a : b;
  }
}

__global__ __launch_bounds__(1024) void bor_merge(const unsigned long long* __restrict__ rowbest,
                                                  int* __restrict__ comp,
                                                  int2* __restrict__ edges,
                                                  int* __restrict__ cnt,
                                                  int* __restrict__ done) {
  const int tree = blockIdx.x;
  if (done[tree]) return;
  const unsigned long long* __restrict__ rb = rowbest + tree * B_N;
  int* __restrict__ cp = comp + tree * B_N;
  int2* __restrict__ eo = edges + (size_t)tree * (B_N - 1);
  int* __restrict__ cn = cnt + tree;
  __shared__ unsigned long long bc[B_N];
  __shared__ int hk[B_N];
  __shared__ int allsame;
  const int t = threadIdx.x;

#pragma unroll
  for (int q = 0; q < 2; ++q) bc[t + q * 1024] = ~0ull;
  __syncthreads();

#pragma unroll
  for (int q = 0; q < 2; ++q) {
    const int i = t + q * 1024;
    const unsigned long long key = rb[i];
    if (key != ~0ull) atomicMin(&bc[cp[i]], key);
  }
  __syncthreads();

  unsigned long long mykey[2];
#pragma unroll
  for (int q = 0; q < 2; ++q) {
    const int c = t + q * 1024;
    const unsigned long long key = bc[c];
    mykey[q] = key;
    int h = c;
    if (key != ~0ull) h = cp[(unsigned)key & (unsigned)(B_N - 1)];
    hk[c] = h;
  }
  __syncthreads();

  int rloc[2];
#pragma unroll
  for (int q = 0; q < 2; ++q) {
    const int c = t + q * 1024;
    const unsigned long long key = mykey[q];
    const int h = hk[c];
    const int hh = hk[h];
    const bool valid = key != ~0ull;
    const bool two = (h != c) && (hh == c);
    rloc[q] = (two && c < h) ? c : h;
    if (valid && (!two || c < h)) {
      int e = atomicAdd(cn, 1);
      eo[e] = make_int2((int)((key >> 11) & (unsigned)(B_N - 1)),
                        (int)(key & (unsigned)(B_N - 1)));
    }
  }
  __syncthreads();
#pragma unroll
  for (int q = 0; q < 2; ++q) hk[t + q * 1024] = rloc[q];
  if (t == 0) allsame = 1;
  __syncthreads();

  for (int it = 0; it < 11; ++it) {
    const int v0 = hk[hk[t]];
    const int v1 = hk[hk[t + 1024]];
    __syncthreads();
    hk[t] = v0;
    hk[t + 1024] = v1;
    __syncthreads();
  }

#pragma unroll
  for (int q = 0; q < 2; ++q) {
    const int v = t + q * 1024;
    cp[v] = hk[cp[v]];
  }
  __syncthreads();
  const int c0v = cp[0];
  if (cp[t] != c0v || cp[t + 1024] != c0v) allsame = 0;
  __syncthreads();
  if (t == 0 && allsame) done[tree] = 1;
}

// ---------------- final: signature sums + rec loss ----------------
__global__ __launch_bounds__(256) void final_k(const float* __restrict__ d2x,
                                               const float* __restrict__ d2z,
                                               const int2* __restrict__ edges,
                                               const float* __restrict__ accum,
                                               const float* __restrict__ latent_norm,
                                               float* __restrict__ out) {
  const int t = threadIdx.x;
  const float maxd = sqrtf(__uint_as_float(((const unsigned*)accum)[1]));
  const float inv_maxd = 1.0f / maxd;
  const float inv_ln = 1.0f / latent_norm[0];
  float local = 0.f;
  for (int e = t; e < 2 * (B_N - 1); e += 256) {
    int2 ij = edges[e];
    size_t idx = (size_t)ij.x * B_N + ij.y;
    float xd = sqrtf(d2x[idx]) * inv_maxd;
    float zd = sqrtf(d2z[idx]) * inv_ln;
    float d = xd - zd;
    local += d * d;
  }
  float topo = block_sum256(local);
  if (t == 0)
    out[0] = accum[0] * (1.0f / ((float)B_N * (float)D_N)) + topo * (1.0f / (float)B_N);
}

// ---------------- launcher ----------------
extern "C" void kernel_launch(void* const* d_in, const int* in_sizes, int n_in,
                              void* d_out, int out_size, void* d_ws, size_t ws_size,
                              hipStream_t stream) {
  const float* x  = (const float*)d_in[0];
  const float* W1 = (const float*)d_in[1];
  const float* b1 = (const float*)d_in[2];
  const float* W2 = (const float*)d_in[3];
  const float* b2 = (const float*)d_in[4];
  const float* W3 = (const float*)d_in[5];
  const float* b3 = (const float*)d_in[6];
  const float* W4 = (const float*)d_in[7];
  const float* b4 = (const float*)d_in[8];
  const float* latent_norm = (const float*)d_in[9];
  float* out = (float*)d_out;

  char* ws = (char*)d_ws;
  size_t off = 0;
  auto alloc = [&](size_t bytes) {
    size_t o = off;
    off += (bytes + 255) & ~(size_t)255;
    return o;
  };
  unsigned short* xb   = (unsigned short*)(ws + alloc((size_t)B_N * D_N * 2));
  unsigned short* w1bt = (unsigned short*)(ws + alloc((size_t)H_N * D_N * 2));
  unsigned short* w4bt = (unsigned short*)(ws + alloc((size_t)D_N * H_N * 2));
  unsigned short* h1b  = (unsigned short*)(ws + alloc((size_t)B_N * H_N * 2));
  unsigned short* h2b  = (unsigned short*)(ws + alloc((size_t)B_N * H_N * 2));
  float* z    = (float*)(ws + alloc((size_t)B_N * L_N * 4));
  float* sqx  = (float*)(ws + alloc((size_t)B_N * 4));
  float* sqz  = (float*)(ws + alloc((size_t)B_N * 4));
  float* d2x  = (float*)(ws + alloc((size_t)B_N * B_N * 4));
  float* d2z  = (float*)(ws + alloc((size_t)B_N * B_N * 4));
  int2* edges = (int2*)(ws + alloc((size_t)2 * (B_N - 1) * sizeof(int2)));
  float* accum = (float*)(ws + alloc(256));        // [0]=rec_sum, [1]=max d2x bits
  int* comp   = (int*)(ws + alloc((size_t)2 * B_N * 4));
  unsigned long long* rowbest = (unsigned long long*)(ws + alloc((size_t)2 * B_N * 8));
  unsigned long long* nn = (unsigned long long*)(ws + alloc((size_t)2 * B_N * NNK * 8));
  int* cnt    = (int*)(ws + alloc(256));
  int* done   = (int*)(ws + alloc(256));
  float* parts = (float*)(ws + alloc((size_t)SPLK * NTILE * 16384 * 4));

  // prep (block B_N also does state init)
  prep_x<<<B_N + 1, 256, 0, stream>>>(x, xb, sqx, accum, comp, cnt, done);
  transpose2<<<8192, dim3(32, 8), 0, stream>>>(W1, W4, w1bt, w4bt);

  // h1 = relu(x@W1 + b1) via split-K + finalize (panel-packed output)
  gemm_splitk<<<dim3(H_N / 128, B_N / 128, SPLK), 256, 0, stream>>>(
      xb, w1bt, B_N, H_N, D_N / SPLK, H_N, parts);
  fin_bias_relu<<<(B_N * H_N) / 1024, 256, 0, stream>>>(parts, b1, h1b);

  g2_k<<<B_N / 4, 256, 0, stream>>>(h1b, W2, b2, z, sqz);
  g3_k<<<dim3(B_N / 4, H_N / 256), 256, 0, stream>>>(z, W3, b3, h2b);
  gemm_recloss<<<dim3(D_N / 128, B_N / 128), 256, 0, stream>>>(h2b, w4bt, b4, x, accum);

  // d2x lower-triangle split-K + mirrored finalize
  gemm_d2_tri<<<dim3(NTILE, 1, SPLK), 256, 0, stream>>>(xb, parts);
  fin_d2_tri<<<dim3(4, NTILE), 256, 0, stream>>>(parts, sqx, d2x, (unsigned*)(accum + 1));

  d2z_k<<<dim3(B_N / 16, B_N / 16), 256, 0, stream>>>(z, sqz, d2z);

  // exact top-16 neighbor lists, then Boruvka (11 rounds max; converged -> no-op)
  topk_k<<<dim3(B_N, 2), 256, 0, stream>>>(d2x, d2z, nn);
  for (int r = 0; r < 11; ++r) {
    bor_scan<<<dim3(B_N, 2), 256, 0, stream>>>(d2x, d2z, comp, nn, rowbest, done);
    bor_merge<<<2, 1024, 0, stream>>>(rowbest, comp, edges, cnt, done);
  }
  final_k<<<1, 256, 0, stream>>>(d2x, d2z, edges, accum, latent_norm, out);
}

// Round 10
// 405.045 us; speedup vs baseline: 1.1405x; 1.1405x over previous
//
#include <hip/hip_runtime.h>
#include <hip/hip_bf16.h>

#define B_N 2048
#define D_N 4096
#define H_N 1024
#define L_N 64
#define NTILE 136  // 16*17/2 lower-triangle 128x128 tiles
#define SPLK 4

typedef __attribute__((ext_vector_type(8))) short short8;
typedef __attribute__((ext_vector_type(4))) float float4_t;

#define ASG __attribute__((address_space(1)))
#define ASL __attribute__((address_space(3)))

__device__ inline float bf2f(unsigned short u) {
  union { unsigned u; float f; } v; v.u = ((unsigned)u) << 16; return v.f;
}
__device__ inline unsigned short f2bf(float f) {
  union { float f; unsigned u; } v; v.f = f;
  unsigned r = v.u + 0x7fffu + ((v.u >> 16) & 1u);
  return (unsigned short)(r >> 16);
}

__device__ inline float block_sum256(float v) {
  const int lane = threadIdx.x & 63, wave = threadIdx.x >> 6;
#pragma unroll
  for (int off = 32; off; off >>= 1) v += __shfl_xor(v, off);
  __shared__ float red_s[4];
  if (lane == 0) red_s[wave] = v;
  __syncthreads();
  return red_s[0] + red_s[1] + red_s[2] + red_s[3];
}

__device__ inline float block_max256(float v) {
  const int lane = threadIdx.x & 63, wave = threadIdx.x >> 6;
#pragma unroll
  for (int off = 32; off; off >>= 1) v = fmaxf(v, __shfl_xor(v, off));
  __shared__ float redm_s[4];
  if (lane == 0) redm_s[wave] = v;
  __syncthreads();
  return fmaxf(fmaxf(redm_s[0], redm_s[1]), fmaxf(redm_s[2], redm_s[3]));
}

__device__ inline void tri_idx(int b, int& tm, int& tn) {
  int m = (int)((sqrtf(8.f * (float)b + 1.f) - 1.f) * 0.5f);
  while ((m + 1) * (m + 2) / 2 <= b) ++m;
  while (m * (m + 1) / 2 > b) --m;
  tm = m;
  tn = b - m * (m + 1) / 2;
}

// ---------------- mega_prep: x cast/pack + state init + both weight transposes ----------
__global__ __launch_bounds__(256) void mega_prep(const float* __restrict__ x,
                                                 const float* __restrict__ W1,
                                                 const float* __restrict__ W4,
                                                 unsigned short* __restrict__ xb,
                                                 unsigned short* __restrict__ w1bt,
                                                 unsigned short* __restrict__ w4bt,
                                                 float* __restrict__ sqx,
                                                 float* __restrict__ accum,
                                                 int* __restrict__ comp,
                                                 unsigned long long* __restrict__ rowbest,
                                                 int* __restrict__ cnt,
                                                 int* __restrict__ done) {
  const int b = blockIdx.x;
  const int t = threadIdx.x;
  if (b < B_N) {  // pack x row b
    const float4* xr = (const float4*)(x + (size_t)b * D_N);
    float s = 0.f;
    for (int i = t; i < D_N / 4; i += 256) {
      float4 v = xr[i];
      s += v.x * v.x + v.y * v.y + v.z * v.z + v.w * v.w;
      ushort4 o;
      o.x = f2bf(v.x); o.y = f2bf(v.y); o.z = f2bf(v.z); o.w = f2bf(v.w);
      const int p = i >> 3;
      const int k31 = (4 * i) & 31;
      *(ushort4*)(xb + ((size_t)p * B_N + b) * 32 + k31) = o;
    }
    float tot = block_sum256(s);
    if (t == 0) sqx[b] = tot;
    return;
  }
  if (b == B_N) {  // state init
    if (t < 2) { accum[t] = 0.f; cnt[t] = 0; done[t] = 0; }
    for (int v = t; v < 2 * B_N; v += 256) {
      comp[v] = v & (B_N - 1);
      rowbest[v] = ~0ull;
    }
    return;
  }
  // transpose-cast (K-panel layout)
  int tb = b - (B_N + 1);
  const float* in;
  unsigned short* out;
  int C, bx, by;
  if (tb < 4096) { in = W1; out = w1bt; C = H_N; bx = tb & 31;  by = tb >> 5; }
  else { tb -= 4096; in = W4; out = w4bt; C = D_N; bx = tb & 127; by = tb >> 7; }
  const int c0 = bx * 32, r0 = by * 32;
  const int tx = t & 31, ty = t >> 5;
  __shared__ float tile[32][33];
#pragma unroll
  for (int i = 0; i < 32; i += 8)
    tile[ty + i][tx] = in[(size_t)(r0 + ty + i) * C + c0 + tx];
  __syncthreads();
#pragma unroll
  for (int i = 0; i < 32; i += 8)
    out[((size_t)(r0 >> 5) * C + c0 + ty + i) * 32 + tx] = f2bf(tile[tx][ty + i]);
}

// ---------------- MFMA GEMM mainloop (128x128 tile, BK=32, 256 threads) ----------------
__device__ inline void gemm_mainloop(const unsigned short* __restrict__ A,
                                     const unsigned short* __restrict__ Bt,
                                     int nrA, int nrB, int Klen, int m_base, int n_base,
                                     float4_t acc[4][4]) {
  __shared__ unsigned short lA[128 * 32];
  __shared__ unsigned short lB[128 * 32];
  const int t = threadIdx.x;
  const int wave = t >> 6;
  const int lane = t & 63;
  const int lrow = lane & 15;
  const int quad = lane >> 4;
  const int wm = (wave & 1) * 64;
  const int wn = (wave >> 1) * 64;
  const int srow = lane >> 2;
  const int scol = (lane & 3) * 8;

  for (int k0 = 0; k0 < Klen; k0 += 32) {
    const size_t pA = (size_t)(k0 >> 5) * nrA;
    const size_t pB = (size_t)(k0 >> 5) * nrB;
    __syncthreads();
#pragma unroll
    for (int q = 0; q < 2; ++q) {
      const int rbase = wave * 32 + q * 16;
      const int row = rbase + srow;
      __builtin_amdgcn_global_load_lds(
          (ASG void*)(A + (pA + m_base + row) * 32 + scol),
          (ASL void*)(lA + rbase * 32), 16, 0, 0);
      __builtin_amdgcn_global_load_lds(
          (ASG void*)(Bt + (pB + n_base + row) * 32 + scol),
          (ASL void*)(lB + rbase * 32), 16, 0, 0);
    }
    __syncthreads();
    short8 af[4], bfr[4];
#pragma unroll
    for (int f = 0; f < 4; ++f) {
      af[f]  = *(const short8*)(lA + (wm + f * 16 + lrow) * 32 + quad * 8);
      bfr[f] = *(const short8*)(lB + (wn + f * 16 + lrow) * 32 + quad * 8);
    }
#pragma unroll
    for (int fm = 0; fm < 4; ++fm)
#pragma unroll
      for (int fn = 0; fn < 4; ++fn)
        acc[fm][fn] = __builtin_amdgcn_mfma_f32_16x16x32_bf16(af[fm], bfr[fn],
                                                              acc[fm][fn], 0, 0, 0);
  }
}

// ---------------- mega_gemm: G1 split-K (512 blocks) + d2-tri split-K (544) ------------
__global__ __launch_bounds__(256) void mega_gemm(const unsigned short* __restrict__ xb,
                                                 const unsigned short* __restrict__ w1bt,
                                                 float* __restrict__ partsG1,
                                                 float* __restrict__ partsD2) {
  float4_t acc[4][4];
  float4_t z4 = {0.f, 0.f, 0.f, 0.f};
#pragma unroll
  for (int a = 0; a < 4; ++a)
#pragma unroll
    for (int b2 = 0; b2 < 4; ++b2) acc[a][b2] = z4;
  const int b = blockIdx.x;
  const int t = threadIdx.x, wave = t >> 6, lane = t & 63;
  const int lrow = lane & 15, quad = lane >> 4;
  const int wm = (wave & 1) * 64, wn = (wave >> 1) * 64;

  if (b < 512) {
    // G1: h1partial = x@W1 chunk. s = split, tile: m (16) x n (8)
    const int s = b >> 7;
    const int tt = b & 127;
    const int m_base = (tt >> 3) * 128, n_base = (tt & 7) * 128;
    const size_t po = (size_t)(s * 32);  // 32 panels per 1024-K chunk
    gemm_mainloop(xb + po * B_N * 32, w1bt + po * H_N * 32, B_N, H_N, D_N / SPLK,
                  m_base, n_base, acc);
    float* __restrict__ P = partsG1 + (size_t)s * B_N * H_N;
#pragma unroll
    for (int fm = 0; fm < 4; ++fm)
#pragma unroll
      for (int fn = 0; fn < 4; ++fn) {
        const int r0 = m_base + wm + fm * 16 + quad * 4;
        const int c = n_base + wn + fn * 16 + lrow;
#pragma unroll
        for (int r = 0; r < 4; ++r)
          P[(size_t)(r0 + r) * H_N + c] = acc[fm][fn][r];
      }
  } else {
    // d2-tri: XCD-swizzled tile order (t&7 = XCD -> 17-tile tm-band)
    const int c = b - 512;
    const int s = c / NTILE;
    const int tt = c - s * NTILE;
    const int tile = (tt & 7) * 17 + (tt >> 3);
    int tm, tn;
    tri_idx(tile, tm, tn);
    const size_t po = (size_t)(s * 32) * B_N * 32;
    gemm_mainloop(xb + po, xb + po, B_N, B_N, D_N / SPLK, tm * 128, tn * 128, acc);
    float* __restrict__ P = partsD2 + ((size_t)s * NTILE + tile) * 16384;
#pragma unroll
    for (int fm = 0; fm < 4; ++fm)
#pragma unroll
      for (int fn = 0; fn < 4; ++fn) {
        const int lr0 = wm + fm * 16 + quad * 4;
        const int lc = wn + fn * 16 + lrow;
#pragma unroll
        for (int r = 0; r < 4; ++r)
          P[(lr0 + r) * 128 + lc] = acc[fm][fn][r];
      }
  }
}

// ---------------- mega_fin: fin_bias_relu (2048 blocks) + fin_d2_tri (544) -------------
__global__ __launch_bounds__(256) void mega_fin(const float* __restrict__ partsG1,
                                                const float* __restrict__ partsD2,
                                                const float* __restrict__ bias,
                                                const float* __restrict__ sq,
                                                unsigned short* __restrict__ h1b,
                                                float* __restrict__ d2x,
                                                unsigned* __restrict__ max_slot) {
  const int b = blockIdx.x;
  const int t = threadIdx.x;
  if (b < 2048) {  // h1 = bf16(relu(sum partial + b1)), K-panel packed
    const size_t MN = (size_t)B_N * H_N;
    const size_t i4 = ((size_t)b * 256 + t) * 4;
    float4 a = *(const float4*)(partsG1 + i4);
#pragma unroll
    for (int s = 1; s < SPLK; ++s) {
      float4 p = *(const float4*)(partsG1 + s * MN + i4);
      a.x += p.x; a.y += p.y; a.z += p.z; a.w += p.w;
    }
    const int row = (int)(i4 >> 10);
    const int k = (int)(i4 & (H_N - 1));
    float4 bb = *(const float4*)(bias + k);
    ushort4 o;
    o.x = f2bf(fmaxf(a.x + bb.x, 0.f));
    o.y = f2bf(fmaxf(a.y + bb.y, 0.f));
    o.z = f2bf(fmaxf(a.z + bb.z, 0.f));
    o.w = f2bf(fmaxf(a.w + bb.w, 0.f));
    *(ushort4*)(h1b + ((size_t)(k >> 5) * B_N + row) * 32 + (k & 31)) = o;
    return;
  }
  // fin_d2_tri
  const int cidx = b - 2048;
  const int tile = cidx >> 2;
  const int c0 = (cidx & 3) * 32;
  int tm, tn;
  tri_idx(tile, tm, tn);
  __shared__ float lds[32][132];
  const int cc = (t & 7) * 4;
  float lmax = 0.f;
#pragma unroll
  for (int q = 0; q < 4; ++q) {
    const int r = (t >> 3) + 32 * q;
    const float* base = partsD2 + (size_t)tile * 16384 + r * 128 + c0 + cc;
    float4 a = *(const float4*)base;
#pragma unroll
    for (int s = 1; s < SPLK; ++s) {
      float4 p = *(const float4*)(base + (size_t)s * NTILE * 16384);
      a.x += p.x; a.y += p.y; a.z += p.z; a.w += p.w;
    }
    const int i = tm * 128 + r;
    const float si = sq[i];
    float4 sj = *(const float4*)(sq + tn * 128 + c0 + cc);
    float4 v;
    v.x = fmaxf(si + sj.x - 2.f * a.x, 0.f);
    v.y = fmaxf(si + sj.y - 2.f * a.y, 0.f);
    v.z = fmaxf(si + sj.z - 2.f * a.z, 0.f);
    v.w = fmaxf(si + sj.w - 2.f * a.w, 0.f);
    *(float4*)(d2x + (size_t)i * B_N + tn * 128 + c0 + cc) = v;
    lds[cc + 0][r] = v.x;
    lds[cc + 1][r] = v.y;
    lds[cc + 2][r] = v.z;
    lds[cc + 3][r] = v.w;
    lmax = fmaxf(lmax, fmaxf(fmaxf(v.x, v.y), fmaxf(v.z, v.w)));
  }
  __syncthreads();
#pragma unroll
  for (int m = 0; m < 4; ++m) {
    const int lin = t + 256 * m;
    const int cc2 = lin >> 5;
    const int r4 = (lin & 31) * 4;
    float4 w = *(const float4*)(&lds[cc2][r4]);
    *(float4*)(d2x + (size_t)(tn * 128 + c0 + cc2) * B_N + tm * 128 + r4) = w;
  }
  float tot = block_max256(lmax);
  if (t == 0) atomicMax(max_slot, __float_as_uint(tot));
}

// ---------------- g2: z = h1@W2 + b2 (+sqz), one wave per row ----------------
__global__ __launch_bounds__(256) void g2_k(const unsigned short* __restrict__ h1b,
                                            const float* __restrict__ W2,
                                            const float* __restrict__ b2,
                                            float* __restrict__ z,
                                            float* __restrict__ sqz) {
  const int col = threadIdx.x & 63;
  const int row = blockIdx.x * 4 + (threadIdx.x >> 6);
  float a0 = 0.f, a1 = 0.f, a2 = 0.f, a3 = 0.f;
  for (int p = 0; p < H_N / 32; ++p) {
    const unsigned short* hb = h1b + ((size_t)p * B_N + row) * 32;
    const float* wb = W2 + (p * 32) * L_N + col;
#pragma unroll
    for (int k2 = 0; k2 < 32; k2 += 4) {
      a0 += bf2f(hb[k2 + 0]) * wb[(k2 + 0) * L_N];
      a1 += bf2f(hb[k2 + 1]) * wb[(k2 + 1) * L_N];
      a2 += bf2f(hb[k2 + 2]) * wb[(k2 + 2) * L_N];
      a3 += bf2f(hb[k2 + 3]) * wb[(k2 + 3) * L_N];
    }
  }
  const float zv = (a0 + a1) + (a2 + a3) + b2[col];
  z[(size_t)row * L_N + col] = zv;
  float s = zv * zv;
#pragma unroll
  for (int off = 32; off; off >>= 1) s += __shfl_xor(s, off);
  if (col == 0) sqz[row] = s;
}

// ---------------- mega_g3_d2z: g3 (2048 blocks) + d2z (16384) ----------------
__global__ __launch_bounds__(256) void mega_g3_d2z(const float* __restrict__ z,
                                                   const float* __restrict__ W3,
                                                   const float* __restrict__ b3,
                                                   const float* __restrict__ sqz,
                                                   unsigned short* __restrict__ h2b,
                                                   float* __restrict__ d2z) {
  const int b = blockIdx.x;
  const int t = threadIdx.x;
  if (b < 2048) {  // g3: h2 = bf16(relu(z@W3+b3)) K-panel packed
    const int rg = b & 511, cg = b >> 9;
    const int col = cg * 256 + t;
    const int r0 = rg * 4;
    __shared__ float zr[4][64];
    zr[t >> 6][t & 63] = z[(size_t)(r0 + (t >> 6)) * L_N + (t & 63)];
    __syncthreads();
    const float bc = b3[col];
    float a0 = bc, a1 = bc, a2 = bc, a3 = bc;
#pragma unroll 8
    for (int k = 0; k < 64; ++k) {
      float w = W3[k * H_N + col];
      a0 += zr[0][k] * w;
      a1 += zr[1][k] * w;
      a2 += zr[2][k] * w;
      a3 += zr[3][k] * w;
    }
    const size_t base = ((size_t)(col >> 5) * B_N) * 32 + (col & 31);
    h2b[base + (size_t)(r0 + 0) * 32] = f2bf(fmaxf(a0, 0.f));
    h2b[base + (size_t)(r0 + 1) * 32] = f2bf(fmaxf(a1, 0.f));
    h2b[base + (size_t)(r0 + 2) * 32] = f2bf(fmaxf(a2, 0.f));
    h2b[base + (size_t)(r0 + 3) * 32] = f2bf(fmaxf(a3, 0.f));
    return;
  }
  // d2z 16x16 tile
  const int c = b - 2048;
  const int bi = (c >> 7) * 16, bj = (c & 127) * 16;
  __shared__ float zi[16][65], zj[16][65];
  for (int idx = t; idx < 16 * 64; idx += 256) {
    const int r = idx >> 6, cc = idx & 63;
    zi[r][cc] = z[(size_t)(bi + r) * L_N + cc];
    zj[r][cc] = z[(size_t)(bj + r) * L_N + cc];
  }
  __syncthreads();
  const int ti = t >> 4, tj = t & 15;
  float dot = 0.f;
#pragma unroll 8
  for (int k = 0; k < 64; ++k) dot += zi[ti][k] * zj[tj][k];
  float v = fmaxf(sqz[bi + ti] + sqz[bj + tj] - 2.f * dot, 0.f);
  d2z[(size_t)(bi + ti) * B_N + bj + tj] = v;
}

// ---------------- scan body (full row) ----------------
__device__ inline void scan_row(const float* __restrict__ row, const int* __restrict__ cp,
                                int i, int ci, unsigned long long* __restrict__ dst) {
  const int t = threadIdx.x;
  const unsigned ibase = (unsigned)(i << 11);
  unsigned long long k = ~0ull;
#pragma unroll
  for (int m = 0; m < 2; ++m) {
    const int j4 = (t + m * 256) * 4;
    float4 dv = *(const float4*)(row + j4);
    int4 cj = *(const int4*)(cp + j4);
    if (cj.x != ci) {
      unsigned long long key = (((unsigned long long)__float_as_uint(dv.x)) << 32) | (ibase | (unsigned)(j4 + 0));
      k = key < k ? key : k;
    }
    if (cj.y != ci) {
      unsigned long long key = (((unsigned long long)__float_as_uint(dv.y)) << 32) | (ibase | (unsigned)(j4 + 1));
      k = key < k ? key : k;
    }
    if (cj.z != ci) {
      unsigned long long key = (((unsigned long long)__float_as_uint(dv.z)) << 32) | (ibase | (unsigned)(j4 + 2));
      k = key < k ? key : k;
    }
    if (cj.w != ci) {
      unsigned long long key = (((unsigned long long)__float_as_uint(dv.w)) << 32) | (ibase | (unsigned)(j4 + 3));
      k = key < k ? key : k;
    }
  }
  const int lane = t & 63, wave = t >> 6;
#pragma unroll
  for (int off = 32; off; off >>= 1) {
    unsigned long long o = __shfl_xor(k, off);
    k = o < k ? o : k;
  }
  __shared__ unsigned long long wmin[4];
  if (lane == 0) wmin[wave] = k;
  __syncthreads();
  if (t == 0) {
    unsigned long long a = wmin[0] < wmin[1] ? wmin[0] : wmin[1];
    unsigned long long b = wmin[2] < wmin[3] ? wmin[2] : wmin[3];
    *dst = (a < b) ? a : b;
  }
}

// ---------------- mega_recloss_scan0: recloss GEMM (512) + Boruvka scan round 0 --------
__global__ __launch_bounds__(256) void mega_recloss_scan0(
    const unsigned short* __restrict__ h2b, const unsigned short* __restrict__ w4bt,
    const float* __restrict__ bias, const float* __restrict__ Xref,
    float* __restrict__ acc_slot,
    const float* __restrict__ d2x, const float* __restrict__ d2z,
    const int* __restrict__ comp, unsigned long long* __restrict__ rowbest) {
  const int b = blockIdx.x;
  const int t = threadIdx.x;
  if (b < 512) {  // recloss
    float4_t acc[4][4];
    float4_t z4 = {0.f, 0.f, 0.f, 0.f};
#pragma unroll
    for (int a = 0; a < 4; ++a)
#pragma unroll
      for (int b2 = 0; b2 < 4; ++b2) acc[a][b2] = z4;
    const int m_base = (b >> 5) * 128, n_base = (b & 31) * 128;
    gemm_mainloop(h2b, w4bt, B_N, D_N, H_N, m_base, n_base, acc);
    const int wave = t >> 6, lane = t & 63;
    const int lrow = lane & 15, quad = lane >> 4;
    const int wm = (wave & 1) * 64, wn = (wave >> 1) * 64;
    float local = 0.f;
#pragma unroll
    for (int fm = 0; fm < 4; ++fm)
#pragma unroll
      for (int fn = 0; fn < 4; ++fn) {
        const int r0 = m_base + wm + fm * 16 + quad * 4;
        const int c = n_base + wn + fn * 16 + lrow;
        const float bc = bias[c];
#pragma unroll
        for (int r = 0; r < 4; ++r) {
          float v = acc[fm][fn][r] + bc - Xref[(size_t)(r0 + r) * D_N + c];
          local += v * v;
        }
      }
    float tot = block_sum256(local);
    if (t == 0) atomicAdd(acc_slot, tot);
    return;
  }
  // scan round 0 (rowbest is ~0 -> full scan)
  const int c = b - 512;
  const int i = c & (B_N - 1);
  const int tree = c >> 11;
  const float* __restrict__ d2 = tree ? d2z : d2x;
  const int* __restrict__ cp = comp + tree * B_N;
  scan_row(d2 + (size_t)i * B_N, cp, i, cp[i], rowbest + tree * B_N + i);
}

// ---------------- bor_scan (rounds >=1): monotone rowbest caching ----------------
// Cached key stays exact while its target j remains cross-component (candidate set
// only shrinks as components grow; old min in new set => still min).
__global__ __launch_bounds__(256) void bor_scan(const float* __restrict__ d2x,
                                                const float* __restrict__ d2z,
                                                const int* __restrict__ comp,
                                                unsigned long long* __restrict__ rowbest,
                                                const int* __restrict__ done) {
  const int tree = blockIdx.y;
  if (done[tree]) return;
  const int i = blockIdx.x;
  const int* __restrict__ cp = comp + tree * B_N;
  const int ci = cp[i];
  const unsigned long long prev = rowbest[tree * B_N + i];
  if (prev != ~0ull) {
    const int j = (int)(prev & (unsigned)(B_N - 1));
    if (cp[j] != ci) return;  // cached value still the exact min cross-key
  }
  const float* __restrict__ d2 = tree ? d2z : d2x;
  scan_row(d2 + (size_t)i * B_N, cp, i, ci, rowbest + tree * B_N + i);
}

// ---------------- bor_merge (unchanged semantics) ----------------
__global__ __launch_bounds__(1024) void bor_merge(const unsigned long long* __restrict__ rowbest,
                                                  int* __restrict__ comp,
                                                  int2* __restrict__ edges,
                                                  int* __restrict__ cnt,
                                                  int* __restrict__ done) {
  const int tree = blockIdx.x;
  if (done[tree]) return;
  const unsigned long long* __restrict__ rb = rowbest + tree * B_N;
  int* __restrict__ cp = comp + tree * B_N;
  int2* __restrict__ eo = edges + (size_t)tree * (B_N - 1);
  int* __restrict__ cn = cnt + tree;
  __shared__ unsigned long long bc[B_N];
  __shared__ int hk[B_N];
  __shared__ int allsame;
  const int t = threadIdx.x;

#pragma unroll
  for (int q = 0; q < 2; ++q) bc[t + q * 1024] = ~0ull;
  __syncthreads();
#pragma unroll
  for (int q = 0; q < 2; ++q) {
    const int i = t + q * 1024;
    const unsigned long long key = rb[i];
    if (key != ~0ull) atomicMin(&bc[cp[i]], key);
  }
  __syncthreads();

  unsigned long long mykey[2];
#pragma unroll
  for (int q = 0; q < 2; ++q) {
    const int c = t + q * 1024;
    const unsigned long long key = bc[c];
    mykey[q] = key;
    int h = c;
    if (key != ~0ull) h = cp[(unsigned)key & (unsigned)(B_N - 1)];
    hk[c] = h;
  }
  __syncthreads();

  int rloc[2];
#pragma unroll
  for (int q = 0; q < 2; ++q) {
    const int c = t + q * 1024;
    const unsigned long long key = mykey[q];
    const int h = hk[c];
    const int hh = hk[h];
    const bool valid = key != ~0ull;
    const bool two = (h != c) && (hh == c);
    rloc[q] = (two && c < h) ? c : h;
    if (valid && (!two || c < h)) {
      int e = atomicAdd(cn, 1);
      eo[e] = make_int2((int)((key >> 11) & (unsigned)(B_N - 1)),
                        (int)(key & (unsigned)(B_N - 1)));
    }
  }
  __syncthreads();
#pragma unroll
  for (int q = 0; q < 2; ++q) hk[t + q * 1024] = rloc[q];
  if (t == 0) allsame = 1;
  __syncthreads();

  for (int it = 0; it < 11; ++it) {
    const int v0 = hk[hk[t]];
    const int v1 = hk[hk[t + 1024]];
    __syncthreads();
    hk[t] = v0;
    hk[t + 1024] = v1;
    __syncthreads();
  }

#pragma unroll
  for (int q = 0; q < 2; ++q) {
    const int v = t + q * 1024;
    cp[v] = hk[cp[v]];
  }
  __syncthreads();
  const int c0v = cp[0];
  if (cp[t] != c0v || cp[t + 1024] != c0v) allsame = 0;
  __syncthreads();
  if (t == 0 && allsame) done[tree] = 1;
}

// ---------------- final ----------------
__global__ __launch_bounds__(256) void final_k(const float* __restrict__ d2x,
                                               const float* __restrict__ d2z,
                                               const int2* __restrict__ edges,
                                               const float* __restrict__ accum,
                                               const float* __restrict__ latent_norm,
                                               float* __restrict__ out) {
  const int t = threadIdx.x;
  const float maxd = sqrtf(__uint_as_float(((const unsigned*)accum)[1]));
  const float inv_maxd = 1.0f / maxd;
  const float inv_ln = 1.0f / latent_norm[0];
  float local = 0.f;
  for (int e = t; e < 2 * (B_N - 1); e += 256) {
    int2 ij = edges[e];
    size_t idx = (size_t)ij.x * B_N + ij.y;
    float xd = sqrtf(d2x[idx]) * inv_maxd;
    float zd = sqrtf(d2z[idx]) * inv_ln;
    float d = xd - zd;
    local += d * d;
  }
  float topo = block_sum256(local);
  if (t == 0)
    out[0] = accum[0] * (1.0f / ((float)B_N * (float)D_N)) + topo * (1.0f / (float)B_N);
}

// ---------------- launcher ----------------
extern "C" void kernel_launch(void* const* d_in, const int* in_sizes, int n_in,
                              void* d_out, int out_size, void* d_ws, size_t ws_size,
                              hipStream_t stream) {
  const float* x  = (const float*)d_in[0];
  const float* W1 = (const float*)d_in[1];
  const float* b1 = (const float*)d_in[2];
  const float* W2 = (const float*)d_in[3];
  const float* b2 = (const float*)d_in[4];
  const float* W3 = (const float*)d_in[5];
  const float* b3 = (const float*)d_in[6];
  const float* W4 = (const float*)d_in[7];
  const float* b4 = (const float*)d_in[8];
  const float* latent_norm = (const float*)d_in[9];
  float* out = (float*)d_out;

  char* ws = (char*)d_ws;
  size_t off = 0;
  auto alloc = [&](size_t bytes) {
    size_t o = off;
    off += (bytes + 255) & ~(size_t)255;
    return o;
  };
  unsigned short* xb   = (unsigned short*)(ws + alloc((size_t)B_N * D_N * 2));
  unsigned short* w1bt = (unsigned short*)(ws + alloc((size_t)H_N * D_N * 2));
  unsigned short* w4bt = (unsigned short*)(ws + alloc((size_t)D_N * H_N * 2));
  unsigned short* h1b  = (unsigned short*)(ws + alloc((size_t)B_N * H_N * 2));
  unsigned short* h2b  = (unsigned short*)(ws + alloc((size_t)B_N * H_N * 2));
  float* z    = (float*)(ws + alloc((size_t)B_N * L_N * 4));
  float* sqx  = (float*)(ws + alloc((size_t)B_N * 4));
  float* sqz  = (float*)(ws + alloc((size_t)B_N * 4));
  float* d2x  = (float*)(ws + alloc((size_t)B_N * B_N * 4));
  float* d2z  = (float*)(ws + alloc((size_t)B_N * B_N * 4));
  int2* edges = (int2*)(ws + alloc((size_t)2 * (B_N - 1) * sizeof(int2)));
  float* accum = (float*)(ws + alloc(256));
  int* comp   = (int*)(ws + alloc((size_t)2 * B_N * 4));
  unsigned long long* rowbest = (unsigned long long*)(ws + alloc((size_t)2 * B_N * 8));
  int* cnt    = (int*)(ws + alloc(256));
  int* done   = (int*)(ws + alloc(256));
  float* partsG1 = (float*)(ws + alloc((size_t)SPLK * B_N * H_N * 4));     // 32 MB
  float* partsD2 = (float*)(ws + alloc((size_t)SPLK * NTILE * 16384 * 4)); // 35.7 MB

  // 1: pack x + init + both transposes
  mega_prep<<<B_N + 1 + 8192, 256, 0, stream>>>(x, W1, W4, xb, w1bt, w4bt, sqx,
                                                accum, comp, rowbest, cnt, done);
  // 2: G1 split-K + d2-tri split-K in one dispatch (1056 blocks)
  mega_gemm<<<512 + SPLK * NTILE, 256, 0, stream>>>(xb, w1bt, partsG1, partsD2);
  // 3: both finalizers
  mega_fin<<<2048 + 4 * NTILE, 256, 0, stream>>>(partsG1, partsD2, b1, sqx, h1b, d2x,
                                                 (unsigned*)(accum + 1));
  // 4: z + sqz
  g2_k<<<B_N / 4, 256, 0, stream>>>(h1b, W2, b2, z, sqz);
  // 5: h2 + d2z
  mega_g3_d2z<<<2048 + 16384, 256, 0, stream>>>(z, W3, b3, sqz, h2b, d2z);
  // 6: recloss + Boruvka scan round 0
  mega_recloss_scan0<<<512 + 2 * B_N, 256, 0, stream>>>(h2b, w4bt, b4, x, accum,
                                                        d2x, d2z, comp, rowbest);
  // 7..: merge0, then 10 cached scan+merge rounds
  bor_merge<<<2, 1024, 0, stream>>>(rowbest, comp, edges, cnt, done);
  for (int r = 1; r < 11; ++r) {
    bor_scan<<<dim3(B_N, 2), 256, 0, stream>>>(d2x, d2z, comp, rowbest, done);
    bor_merge<<<2, 1024, 0, stream>>>(rowbest, comp, edges, cnt, done);
  }
  final_k<<<1, 256, 0, stream>>>(d2x, d2z, edges, accum, latent_norm, out);
}